// Round 1
// baseline (6824.029 us; speedup 1.0000x reference)
//
#include <hip/hip_runtime.h>
#include <hip/hip_bf16.h>
#include <math.h>

#define T_STEPS 8
#define NNODES 50000
#define NEDGES 800000
#define FDIM 128
#define HDIM 128
#define G4 512

// ------------------------- CSR build -------------------------
__global__ void count_kernel(const int* __restrict__ dst, int* __restrict__ cnt) {
    int e = blockIdx.x * blockDim.x + threadIdx.x;
    if (e < NEDGES) atomicAdd(&cnt[dst[e]], 1);
}

__global__ void nis_kernel(const int* __restrict__ cnt, float* __restrict__ nis) {
    int n = blockIdx.x * blockDim.x + threadIdx.x;
    if (n < NNODES) nis[n] = rsqrtf((float)cnt[n] + 1.0f);
}

// single-block exclusive scan over cnt[0..N-1] -> ptr[0..N]
__global__ void scan_kernel(const int* __restrict__ cnt, int* __restrict__ ptr) {
    __shared__ int sdata[1024];
    __shared__ int carry_s;
    int tid = threadIdx.x;
    if (tid == 0) carry_s = 0;
    __syncthreads();
    for (int base = 0; base < NNODES; base += 1024) {
        int v = (base + tid < NNODES) ? cnt[base + tid] : 0;
        sdata[tid] = v;
        __syncthreads();
        for (int off = 1; off < 1024; off <<= 1) {
            int t = (tid >= off) ? sdata[tid - off] : 0;
            __syncthreads();
            sdata[tid] += t;
            __syncthreads();
        }
        int incl = sdata[tid];
        int carry = carry_s;
        if (base + tid < NNODES) ptr[base + tid] = carry + incl - v;
        __syncthreads();
        if (tid == 1023) carry_s = carry + sdata[1023];
        __syncthreads();
    }
    if (tid == 0) ptr[NNODES] = carry_s;
}

__global__ void fill_kernel(const int* __restrict__ src, const int* __restrict__ dst,
                            const int* __restrict__ ptr, int* __restrict__ cur,
                            int* __restrict__ csr) {
    int e = blockIdx.x * blockDim.x + threadIdx.x;
    if (e < NEDGES) {
        int d = dst[e];
        int pos = ptr[d] + atomicAdd(&cur[d], 1);
        csr[pos] = src[e];
    }
}

// ------------------------- GCN aggregate -------------------------
// Ls holds (X@W + b) * nis[row].  out[d] = relu(nis[d] * (Ls[d] + sum_{src->d} Ls[src]))
__global__ void gcn_agg_kernel(const float* __restrict__ Ls, const float* __restrict__ nis,
                               const int* __restrict__ ptr, const int* __restrict__ csr,
                               float* __restrict__ out) {
    int d = blockIdx.x;
    int f = threadIdx.x;
    int beg = ptr[d], end = ptr[d + 1];
    float acc = Ls[(size_t)d * HDIM + f];
    for (int i = beg; i < end; ++i) {
        int s = csr[i];
        acc += Ls[(size_t)s * HDIM + f];
    }
    float v = acc * nis[d];
    out[(size_t)d * HDIM + f] = v > 0.f ? v : 0.f;
}

// ------------------------- GEMM -------------------------
// C[M,NC] = A @ B (+bias) with options:
//   BT:    B is stored [NC][128] row-major (use B^T), else [K][NC] row-major
//   DUAL:  K = 256 virtual; first 128 from (A1,B1), second 128 from (A2,B2); bias1+bias2
//   SCALE: multiply output row by nis[r]
template <int KTOT, bool BT, bool DUAL, bool SCALE>
__global__ __launch_bounds__(256) void gemm_kernel(
    const float* __restrict__ A1, const float* __restrict__ A2,
    const float* __restrict__ B1, const float* __restrict__ B2,
    const float* __restrict__ bias1, const float* __restrict__ bias2,
    const float* __restrict__ nis,
    float* __restrict__ C, int M, int NC) {
    __shared__ float As[16][128];
    __shared__ float Bs[16][128];
    int tid = threadIdx.x;
    int rb = blockIdx.x * 128;
    int cb = blockIdx.y * 128;
    int tx = tid & 15, ty = tid >> 4;
    int r0 = ty * 8, c0 = tx * 8;
    float acc[8][8];
#pragma unroll
    for (int i = 0; i < 8; i++)
#pragma unroll
        for (int j = 0; j < 8; j++) acc[i][j] = 0.f;

    for (int kb = 0; kb < KTOT / 16; ++kb) {
        int k0 = kb * 16;
        // ---- stage A tile (transposed into LDS) ----
        {
            const float* Asrc = A1;
            int ak0 = k0;
            if (DUAL && k0 >= 128) { Asrc = A2; ak0 = k0 - 128; }
            int r = tid >> 1;
            int half = tid & 1;
            int row = rb + r;
            float4 v0, v1;
            if (row < M) {
                const float* p = Asrc + (size_t)row * 128 + ak0 + half * 8;
                v0 = *(const float4*)p;
                v1 = *(const float4*)(p + 4);
            } else {
                v0 = make_float4(0, 0, 0, 0);
                v1 = make_float4(0, 0, 0, 0);
            }
            float tmp[8];
            *(float4*)&tmp[0] = v0;
            *(float4*)&tmp[4] = v1;
#pragma unroll
            for (int i = 0; i < 8; i++) As[half * 8 + i][r] = tmp[i];
        }
        // ---- stage B tile ----
        if (BT) {
            const float* Bsrc = B1;
            int bk0 = k0;
            if (DUAL && k0 >= 128) { Bsrc = B2; bk0 = k0 - 128; }
            int j = tid >> 1;
            int half = tid & 1;
            const float* p = Bsrc + (size_t)(cb + j) * 128 + bk0 + half * 8;
            float4 v0 = *(const float4*)p;
            float4 v1 = *(const float4*)(p + 4);
            float tmp[8];
            *(float4*)&tmp[0] = v0;
            *(float4*)&tmp[4] = v1;
#pragma unroll
            for (int i = 0; i < 8; i++) Bs[half * 8 + i][j] = tmp[i];
        } else {
            int k = tid >> 4;
            int cg = (tid & 15) * 8;
            const float* p = B1 + (size_t)(k0 + k) * NC + cb + cg;
            float4 v0 = *(const float4*)p;
            float4 v1 = *(const float4*)(p + 4);
            *(float4*)&Bs[k][cg] = v0;
            *(float4*)&Bs[k][cg + 4] = v1;
        }
        __syncthreads();
#pragma unroll
        for (int kk = 0; kk < 16; ++kk) {
            float av[8], bv[8];
            *(float4*)&av[0] = *(const float4*)&As[kk][r0];
            *(float4*)&av[4] = *(const float4*)&As[kk][r0 + 4];
            *(float4*)&bv[0] = *(const float4*)&Bs[kk][c0];
            *(float4*)&bv[4] = *(const float4*)&Bs[kk][c0 + 4];
#pragma unroll
            for (int i = 0; i < 8; i++)
#pragma unroll
                for (int j = 0; j < 8; j++) acc[i][j] = fmaf(av[i], bv[j], acc[i][j]);
        }
        __syncthreads();
    }
    // ---- epilogue ----
#pragma unroll
    for (int i = 0; i < 8; i++) {
        int r = rb + r0 + i;
        if (r >= M) continue;
        float scale = SCALE ? nis[r] : 1.0f;
        float vals[8];
#pragma unroll
        for (int j = 0; j < 8; j++) {
            int c = cb + c0 + j;
            float b = bias1[c] + (DUAL ? bias2[c] : 0.f);
            vals[j] = (acc[i][j] + b) * scale;
        }
        float* p = C + (size_t)r * NC + cb + c0;
        *(float4*)p = *(float4*)&vals[0];
        *(float4*)(p + 4) = *(float4*)&vals[4];
    }
}

// ------------------------- LSTM elementwise -------------------------
__global__ void lstm_ew_kernel(const float* __restrict__ G, float* __restrict__ c,
                               float* __restrict__ h) {
    int idx = blockIdx.x * blockDim.x + threadIdx.x;
    if (idx >= NNODES * HDIM) return;
    int n = idx >> 7, j = idx & 127;
    const float* g = G + (size_t)n * G4;
    float ig = g[j], fg = g[128 + j], gg = g[256 + j], og = g[384 + j];
    float cv = c[idx];
    float si = 1.f / (1.f + expf(-ig));
    float sf = 1.f / (1.f + expf(-fg));
    float so = 1.f / (1.f + expf(-og));
    float cn = sf * cv + si * tanhf(gg);
    float hn = so * tanhf(cn);
    c[idx] = cn;
    h[idx] = hn;
}

// ------------------------- output projection -------------------------
__global__ void outw_kernel(const float* __restrict__ h2, const float* __restrict__ w,
                            const float* __restrict__ b, float* __restrict__ outs) {
    int wv = threadIdx.x >> 6;
    int lane = threadIdx.x & 63;
    int n = blockIdx.x * 4 + wv;
    if (n >= NNODES) return;
    const float* hr = h2 + (size_t)n * 128;
    float v = hr[lane] * w[lane] + hr[64 + lane] * w[64 + lane];
#pragma unroll
    for (int m = 32; m >= 1; m >>= 1) v += __shfl_xor(v, m, 64);
    if (lane == 0) outs[n] = v + b[0];
}

// ------------------------- launch -------------------------
extern "C" void kernel_launch(void* const* d_in, const int* in_sizes, int n_in,
                              void* d_out, int out_size, void* d_ws, size_t ws_size,
                              hipStream_t stream) {
    const float* x = (const float*)d_in[0];
    const int* eidx = (const int*)d_in[1];
    const float* w1 = (const float*)d_in[2];
    const float* b1 = (const float*)d_in[3];
    const float* w2 = (const float*)d_in[4];
    const float* b2 = (const float*)d_in[5];
    const float* wih1 = (const float*)d_in[6];
    const float* whh1 = (const float*)d_in[7];
    const float* bih1 = (const float*)d_in[8];
    const float* bhh1 = (const float*)d_in[9];
    const float* wih2 = (const float*)d_in[10];
    const float* whh2 = (const float*)d_in[11];
    const float* bih2 = (const float*)d_in[12];
    const float* bhh2 = (const float*)d_in[13];
    const float* outw = (const float*)d_in[14];
    const float* outb = (const float*)d_in[15];

    float* out = (float*)d_out;
    float* outs = out;
    float* h1 = out + (size_t)T_STEPS * NNODES;
    float* c1 = h1 + (size_t)NNODES * HDIM;
    float* h2 = c1 + (size_t)NNODES * HDIM;
    float* c2 = h2 + (size_t)NNODES * HDIM;

    char* ws = (char*)d_ws;
    size_t off = 0;
    auto alloc = [&](size_t bytes) {
        void* p = ws + off;
        off = (off + bytes + 255) & ~(size_t)255;
        return p;
    };
    float* nis = (float*)alloc((size_t)NNODES * 4);
    int* cnt = (int*)alloc((size_t)NNODES * 4);
    int* ptr = (int*)alloc((size_t)(NNODES + 1) * 4);
    int* csr = (int*)alloc((size_t)NEDGES * 4);
    float* bufA = (float*)alloc((size_t)NNODES * HDIM * 4);
    float* bufB = (float*)alloc((size_t)NNODES * HDIM * 4);
    float* bufG = (float*)alloc((size_t)NNODES * G4 * 4);

    // zero LSTM states (h1,c1,h2,c2 are contiguous in d_out)
    hipMemsetAsync(h1, 0, (size_t)4 * NNODES * HDIM * sizeof(float), stream);

    for (int t = 0; t < T_STEPS; ++t) {
        const int* src = eidx + (size_t)t * 2 * NEDGES;
        const int* dst = src + NEDGES;

        // CSR build + degree
        hipMemsetAsync(cnt, 0, (size_t)NNODES * 4, stream);
        count_kernel<<<(NEDGES + 255) / 256, 256, 0, stream>>>(dst, cnt);
        nis_kernel<<<(NNODES + 255) / 256, 256, 0, stream>>>(cnt, nis);
        scan_kernel<<<1, 1024, 0, stream>>>(cnt, ptr);
        hipMemsetAsync(cnt, 0, (size_t)NNODES * 4, stream);
        fill_kernel<<<(NEDGES + 255) / 256, 256, 0, stream>>>(src, dst, ptr, cnt, csr);

        // GCN layer 1
        const float* xt = x + (size_t)t * NNODES * FDIM;
        dim3 g1((NNODES + 127) / 128, 1);
        gemm_kernel<128, false, false, true><<<g1, 256, 0, stream>>>(
            xt, nullptr, w1, nullptr, b1, nullptr, nis, bufA, NNODES, 128);
        gcn_agg_kernel<<<NNODES, 128, 0, stream>>>(bufA, nis, ptr, csr, bufB);
        // GCN layer 2
        gemm_kernel<128, false, false, true><<<g1, 256, 0, stream>>>(
            bufB, nullptr, w2, nullptr, b2, nullptr, nis, bufA, NNODES, 128);
        gcn_agg_kernel<<<NNODES, 128, 0, stream>>>(bufA, nis, ptr, csr, bufB);
        // bufB = feats[t]

        // LSTM cell 1
        dim3 g2((NNODES + 127) / 128, 4);
        gemm_kernel<256, true, true, false><<<g2, 256, 0, stream>>>(
            bufB, h1, wih1, whh1, bih1, bhh1, nullptr, bufG, NNODES, 512);
        lstm_ew_kernel<<<(NNODES * HDIM + 255) / 256, 256, 0, stream>>>(bufG, c1, h1);
        // LSTM cell 2
        gemm_kernel<256, true, true, false><<<g2, 256, 0, stream>>>(
            h1, h2, wih2, whh2, bih2, bhh2, nullptr, bufG, NNODES, 512);
        lstm_ew_kernel<<<(NNODES * HDIM + 255) / 256, 256, 0, stream>>>(bufG, c2, h2);
        // output projection
        outw_kernel<<<(NNODES + 3) / 4, 256, 0, stream>>>(h2, outw, outb,
                                                          outs + (size_t)t * NNODES);
    }
}